// Round 3
// baseline (154.936 us; speedup 1.0000x reference)
//
#include <hip/hip_runtime.h>
#include <cstddef>

#define XSZ 512
#define YSZ 512
#define NB  4
#define NC  64
#define NP  20000

// ---------------------------------------------------------------------------
// Transpose [B,C,H,W] -> [B,H,W,C]  (writes coalesced; reads strided but tiny
// and L2-resident: total images = 10.3 MB)
// ---------------------------------------------------------------------------
__global__ void k_transpose(const float* __restrict__ in, float* __restrict__ out,
                            int H, int W, int total) {
    int idx = blockIdx.x * blockDim.x + threadIdx.x;
    if (idx >= total) return;
    int c = idx & (NC - 1);
    int t = idx >> 6;            // b*H*W + h*W + w
    int w = t % W; t /= W;
    int h = t % H;
    int b = t / H;
    out[idx] = in[(((size_t)b * NC + c) * H + h) * W + w];
}

// ---------------------------------------------------------------------------
// Scatter: winner[b][cx][cy] = max point-index p with contains>0 mapping there
// (numpy fancy-assignment duplicate semantics = last write wins = max p)
// ---------------------------------------------------------------------------
__global__ void k_scatter(const int* __restrict__ coors, const int* __restrict__ contains,
                          int* __restrict__ winner) {
    int idx = blockIdx.x * blockDim.x + threadIdx.x;   // b*NP + p
    if (idx >= NB * NP) return;
    if (contains[idx] <= 0) return;
    int b  = idx / NP;
    int p  = idx - b * NP;
    int cx = coors[idx * 3 + 1];
    int cy = coors[idx * 3 + 2];
    if ((unsigned)cx >= XSZ || (unsigned)cy >= YSZ) return;   // mode='drop'
    atomicMax(&winner[((size_t)b * XSZ + cx) * YSZ + cy], p);
}

// ---------------------------------------------------------------------------
// Compact: one record per non-empty cell (only the winning point emits)
// rec = { packed(b,cx,cy), px, py, unused }
// ---------------------------------------------------------------------------
__global__ void k_compact(const int* __restrict__ coors, const int* __restrict__ contains,
                          const float* __restrict__ pnts, const int* __restrict__ winner,
                          int* __restrict__ counter, float4* __restrict__ recs) {
    int idx = blockIdx.x * blockDim.x + threadIdx.x;
    if (idx >= NB * NP) return;
    if (contains[idx] <= 0) return;
    int b  = idx / NP;
    int p  = idx - b * NP;
    int cx = coors[idx * 3 + 1];
    int cy = coors[idx * 3 + 2];
    if ((unsigned)cx >= XSZ || (unsigned)cy >= YSZ) return;
    if (winner[((size_t)b * XSZ + cx) * YSZ + cy] != p) return;
    int slot = atomicAdd(counter, 1);
    int packed = (b << 20) | (cx << 10) | cy;
    recs[slot] = make_float4(__int_as_float(packed),
                             pnts[idx * 2 + 0], pnts[idx * 2 + 1], 0.0f);
}

// ---------------------------------------------------------------------------
// Bilinear sample, exact replay of reference f32 arithmetic.
// Element address: base + (yc*W + xc)*sElem + c*sChan
//   transposed [H,W,C]: sElem=64, sChan=1   (coalesced 256B per tap per wave)
//   original  [C,H,W]: sElem=1,  sChan=H*W  (fallback if ws too small)
// ---------------------------------------------------------------------------
__device__ __forceinline__ float bilin(const float* __restrict__ img, int H, int W,
                                       float px, float py, int c, int sElem, int sChan) {
    float gx = px * 2.0f - 1.0f;               // pnts*2-1  (grid value)
    float gy = py * 2.0f - 1.0f;
    float x = (gx + 1.0f) * 0.5f * (float)(W - 1);
    float y = (gy + 1.0f) * 0.5f * (float)(H - 1);
    float x0f = floorf(x), y0f = floorf(y);
    float wx1 = x - x0f,   wy1 = y - y0f;
    float wx0 = 1.0f - wx1, wy0 = 1.0f - wy1;
    int x0 = (int)x0f, y0 = (int)y0f;
    float acc = 0.0f;
#pragma unroll
    for (int dy = 0; dy < 2; ++dy) {
#pragma unroll
        for (int dx = 0; dx < 2; ++dx) {
            int xi = x0 + dx, yi = y0 + dy;
            bool valid = (xi >= 0) && (xi <= W - 1) && (yi >= 0) && (yi <= H - 1);
            int xc = min(max(xi, 0), W - 1);
            int yc = min(max(yi, 0), H - 1);
            float w = (dx ? wx1 : wx0) * (dy ? wy1 : wy0);
            float v = img[(size_t)(yc * W + xc) * sElem + (size_t)c * sChan];
            acc = fmaf(v, valid ? w : 0.0f, acc);
        }
    }
    return acc;
}

// ---------------------------------------------------------------------------
// Sparse sample: one 64-lane wave per non-empty cell, lane = channel.
// ---------------------------------------------------------------------------
__global__ void __launch_bounds__(64)
k_sample(const float4* __restrict__ recs, const int* __restrict__ counter,
         const float* __restrict__ i3, const float* __restrict__ i4,
         const float* __restrict__ i5, const float* __restrict__ dyn,
         float* __restrict__ out,
         int sElem, int sC3, int sC4, int sC5) {
    int cell = blockIdx.x;
    if (cell >= *counter) return;
    float4 r = recs[cell];
    int packed = __float_as_int(r.x);
    int b  = packed >> 20;
    int cx = (packed >> 10) & 1023;
    int cy = packed & 1023;
    int c  = threadIdx.x;

    const int HW3 = 48 * 160, HW4 = 24 * 80, HW5 = 12 * 40;
    float fa = bilin(i3 + (size_t)b * NC * HW3, 48, 160, r.y, r.z, c, sElem, sC3);
    float fb = bilin(i4 + (size_t)b * NC * HW4, 24, 80,  r.y, r.z, c, sElem, sC4);
    float fc = bilin(i5 + (size_t)b * NC * HW5, 12, 40,  r.y, r.z, c, sElem, sC5);

    size_t dbase = (((size_t)b * 3) * XSZ + cx) * YSZ + cy;
    float d0 = dyn[dbase];
    float d1 = dyn[dbase + (size_t)XSZ * YSZ];
    float d2 = dyn[dbase + (size_t)2 * XSZ * YSZ];

    out[(((size_t)b * NC + c) * XSZ + cx) * YSZ + cy] = fa * d0 + fb * d1 + fc * d2;
}

extern "C" void kernel_launch(void* const* d_in, const int* in_sizes, int n_in,
                              void* d_out, int out_size, void* d_ws, size_t ws_size,
                              hipStream_t stream) {
    const float* c3       = (const float*)d_in[0];
    const float* c4       = (const float*)d_in[1];
    const float* c5       = (const float*)d_in[2];
    const float* dyn      = (const float*)d_in[3];
    const float* pnts     = (const float*)d_in[4];
    const int*   coors    = (const int*)d_in[5];
    const int*   contains = (const int*)d_in[6];
    float* out = (float*)d_out;

    // workspace layout
    char* ws = (char*)d_ws;
    size_t off = 0;
    int* winner = (int*)(ws + off);    off += (size_t)NB * XSZ * YSZ * 4;   // 4 MiB
    int* counter = (int*)(ws + off);   off += 16;
    float4* recs = (float4*)(ws + off); off += (size_t)NB * NP * 16;        // 1.28 MB
    float* c3t = (float*)(ws + off);   off += (size_t)NB * NC * 48 * 160 * 4;
    float* c4t = (float*)(ws + off);   off += (size_t)NB * NC * 24 * 80 * 4;
    float* c5t = (float*)(ws + off);   off += (size_t)NB * NC * 12 * 40 * 4;
    bool useT = (ws_size >= off);      // transpose path needs ~15.8 MB

    // zero output (mandatory: 96% of elements are zero), init winner=-1, count=0
    hipMemsetAsync(d_out, 0, (size_t)out_size * sizeof(float), stream);
    hipMemsetAsync(winner, 0xFF, (size_t)NB * XSZ * YSZ * 4, stream);
    hipMemsetAsync(counter, 0, 4, stream);

    int npts = NB * NP;
    k_scatter<<<(npts + 255) / 256, 256, 0, stream>>>(coors, contains, winner);

    if (useT) {
        int t3 = NB * NC * 48 * 160;
        int t4 = NB * NC * 24 * 80;
        int t5 = NB * NC * 12 * 40;
        k_transpose<<<(t3 + 255) / 256, 256, 0, stream>>>(c3, c3t, 48, 160, t3);
        k_transpose<<<(t4 + 255) / 256, 256, 0, stream>>>(c4, c4t, 24, 80, t4);
        k_transpose<<<(t5 + 255) / 256, 256, 0, stream>>>(c5, c5t, 12, 40, t5);
    }

    k_compact<<<(npts + 255) / 256, 256, 0, stream>>>(coors, contains, pnts,
                                                      winner, counter, recs);

    // max possible non-empty cells = NB*NP; blocks past *counter exit instantly
    if (useT) {
        k_sample<<<npts, 64, 0, stream>>>(recs, counter, c3t, c4t, c5t, dyn, out,
                                          NC, 1, 1, 1);
    } else {
        k_sample<<<npts, 64, 0, stream>>>(recs, counter, c3, c4, c5, dyn, out,
                                          1, 48 * 160, 24 * 80, 12 * 40);
    }
}

// Round 4
// 124.731 us; speedup vs baseline: 1.2422x; 1.2422x over previous
//
#include <hip/hip_runtime.h>
#include <cstddef>

#define XSZ 512
#define YSZ 512
#define NB  4
#define NC  64
#define NP  20000
#define HW3 (48*160)
#define HW4 (24*80)
#define HW5 (12*40)

// ---------------------------------------------------------------------------
// Transpose [B,C,H,W] -> [B,H,W,C]  (writes coalesced; images total 10.3 MB)
// ---------------------------------------------------------------------------
__global__ void k_transpose(const float* __restrict__ in, float* __restrict__ out,
                            int H, int W, int total) {
    int idx = blockIdx.x * blockDim.x + threadIdx.x;
    if (idx >= total) return;
    int c = idx & (NC - 1);
    int t = idx >> 6;            // b*H*W + h*W + w
    int w = t % W; t /= W;
    int h = t % H;
    int b = t / H;
    out[idx] = in[(((size_t)b * NC + c) * H + h) * W + w];
}

// ---------------------------------------------------------------------------
// Scatter: winner[b][cx][cy] = max point-index p with contains>0 (numpy
// fancy-assignment last-write-wins == max p)
// ---------------------------------------------------------------------------
__global__ void k_scatter(const int* __restrict__ coors, const int* __restrict__ contains,
                          int* __restrict__ winner) {
    int idx = blockIdx.x * blockDim.x + threadIdx.x;   // b*NP + p
    if (idx >= NB * NP) return;
    if (contains[idx] <= 0) return;
    int b  = idx / NP;
    int p  = idx - b * NP;
    int cx = coors[idx * 3 + 1];
    int cy = coors[idx * 3 + 2];
    if ((unsigned)cx >= XSZ || (unsigned)cy >= YSZ) return;   // mode='drop'
    atomicMax(&winner[((size_t)b * XSZ + cx) * YSZ + cy], p);
}

// ---------------------------------------------------------------------------
// Compact: winning point emits one record per non-empty cell and RE-ENCODES
// winner[cell] = slot | (1<<30)  (p < 2^30, so no collision; -1 stays empty).
// Losing threads that read winner after the rewrite see slot|2^30 != their p
// and correctly skip.
// ---------------------------------------------------------------------------
__global__ void k_compact(const int* __restrict__ coors, const int* __restrict__ contains,
                          const float* __restrict__ pnts, int* __restrict__ winner,
                          int* __restrict__ counter, float4* __restrict__ recs) {
    int idx = blockIdx.x * blockDim.x + threadIdx.x;
    if (idx >= NB * NP) return;
    if (contains[idx] <= 0) return;
    int b  = idx / NP;
    int p  = idx - b * NP;
    int cx = coors[idx * 3 + 1];
    int cy = coors[idx * 3 + 2];
    if ((unsigned)cx >= XSZ || (unsigned)cy >= YSZ) return;
    size_t cell = ((size_t)b * XSZ + cx) * YSZ + cy;
    if (winner[cell] != p) return;
    int slot = atomicAdd(counter, 1);
    winner[cell] = slot | (1 << 30);
    int packed = (b << 20) | (cx << 10) | cy;
    recs[slot] = make_float4(__int_as_float(packed),
                             pnts[idx * 2 + 0], pnts[idx * 2 + 1], 0.0f);
}

// ---------------------------------------------------------------------------
// Bilinear sample, exact replay of reference f32 arithmetic.
//   transposed [H,W,C]: sElem=64, sChan=1  (coalesced 256B per tap per wave)
//   original  [C,H,W] : sElem=1,  sChan=H*W
// ---------------------------------------------------------------------------
__device__ __forceinline__ float bilin(const float* __restrict__ img, int H, int W,
                                       float px, float py, int c, int sElem, int sChan) {
    float gx = px * 2.0f - 1.0f;
    float gy = py * 2.0f - 1.0f;
    float x = (gx + 1.0f) * 0.5f * (float)(W - 1);
    float y = (gy + 1.0f) * 0.5f * (float)(H - 1);
    float x0f = floorf(x), y0f = floorf(y);
    float wx1 = x - x0f,   wy1 = y - y0f;
    float wx0 = 1.0f - wx1, wy0 = 1.0f - wy1;
    int x0 = (int)x0f, y0 = (int)y0f;
    float acc = 0.0f;
#pragma unroll
    for (int dy = 0; dy < 2; ++dy) {
#pragma unroll
        for (int dx = 0; dx < 2; ++dx) {
            int xi = x0 + dx, yi = y0 + dy;
            bool valid = (xi >= 0) && (xi <= W - 1) && (yi >= 0) && (yi <= H - 1);
            int xc = min(max(xi, 0), W - 1);
            int yc = min(max(yi, 0), H - 1);
            float w = (dx ? wx1 : wx0) * (dy ? wy1 : wy0);
            float v = img[(size_t)(yc * W + xc) * sElem + (size_t)c * sChan];
            acc = fmaf(v, valid ? w : 0.0f, acc);
        }
    }
    return acc;
}

// ---------------------------------------------------------------------------
// Sparse sample: one 64-lane wave per non-empty cell, lane = channel.
// mode 0: write compact cvals[slot*64+c]   (coalesced 256B wave store)
// mode 1: write scattered into out (fallback when ws too small for cvals)
// ---------------------------------------------------------------------------
__global__ void __launch_bounds__(64)
k_sample(const float4* __restrict__ recs, const int* __restrict__ counter,
         const float* __restrict__ i3, const float* __restrict__ i4,
         const float* __restrict__ i5, const float* __restrict__ dyn,
         float* __restrict__ cvals, float* __restrict__ out,
         int sElem, int sC3, int sC4, int sC5, int mode) {
    int cell = blockIdx.x;
    if (cell >= *counter) return;
    float4 r = recs[cell];
    int packed = __float_as_int(r.x);
    int b  = packed >> 20;
    int cx = (packed >> 10) & 1023;
    int cy = packed & 1023;
    int c  = threadIdx.x;

    float fa = bilin(i3 + (size_t)b * NC * HW3, 48, 160, r.y, r.z, c, sElem, sC3);
    float fb = bilin(i4 + (size_t)b * NC * HW4, 24, 80,  r.y, r.z, c, sElem, sC4);
    float fc = bilin(i5 + (size_t)b * NC * HW5, 12, 40,  r.y, r.z, c, sElem, sC5);

    size_t dbase = (((size_t)b * 3) * XSZ + cx) * YSZ + cy;
    float d0 = dyn[dbase];
    float d1 = dyn[dbase + (size_t)XSZ * YSZ];
    float d2 = dyn[dbase + (size_t)2 * XSZ * YSZ];
    float v = fa * d0 + fb * d1 + fc * d2;

    if (mode == 0) {
        cvals[(size_t)cell * NC + c] = v;
    } else {
        out[(((size_t)b * NC + c) * XSZ + cx) * YSZ + cy] = v;
    }
}

// ---------------------------------------------------------------------------
// Dense writer: each block owns one (b,x) row-slab: out[b][:, x, :] (128 KB).
// Winner row loaded once as int4 (registers, reused across all 64 channels);
// every output byte written exactly once, float4-coalesced.
// ---------------------------------------------------------------------------
__global__ void __launch_bounds__(256)
k_writeout(const int* __restrict__ winner, const float* __restrict__ cvals,
           float* __restrict__ out) {
    int bx = blockIdx.x;                 // b*512 + x
    int b = bx >> 9, x = bx & 511;
    const int4* wrow = (const int4*)(winner + ((size_t)b * XSZ + x) * YSZ);
    int4 r = wrow[threadIdx.x & 127];    // this thread's 4 consecutive y cells
    int lane_c = threadIdx.x >> 7;       // 0 or 1
    int y4 = (threadIdx.x & 127) << 2;
    size_t obase = (size_t)b * NC * XSZ * YSZ + (size_t)x * YSZ + y4;

    bool h0 = r.x >= 0, h1 = r.y >= 0, h2 = r.z >= 0, h3 = r.w >= 0;
    size_t s0 = (size_t)(r.x & 0x3FFFFFFF) * NC;
    size_t s1 = (size_t)(r.y & 0x3FFFFFFF) * NC;
    size_t s2 = (size_t)(r.z & 0x3FFFFFFF) * NC;
    size_t s3 = (size_t)(r.w & 0x3FFFFFFF) * NC;

    for (int cb = 0; cb < NC; cb += 2) {
        int c = cb + lane_c;
        float4 v = make_float4(0.f, 0.f, 0.f, 0.f);
        if (h0) v.x = cvals[s0 + c];
        if (h1) v.y = cvals[s1 + c];
        if (h2) v.z = cvals[s2 + c];
        if (h3) v.w = cvals[s3 + c];
        *(float4*)(out + obase + (size_t)c * (XSZ * YSZ)) = v;
    }
}

// ---------------------------------------------------------------------------
// Fallback zero-fill (float4, grid-stride) — beats rocclr fillBufferAligned
// ---------------------------------------------------------------------------
__global__ void k_zero4(float4* __restrict__ p, long n4) {
    long i = (long)blockIdx.x * blockDim.x + threadIdx.x;
    long stride = (long)gridDim.x * blockDim.x;
    for (; i < n4; i += stride) p[i] = make_float4(0.f, 0.f, 0.f, 0.f);
}

extern "C" void kernel_launch(void* const* d_in, const int* in_sizes, int n_in,
                              void* d_out, int out_size, void* d_ws, size_t ws_size,
                              hipStream_t stream) {
    const float* c3       = (const float*)d_in[0];
    const float* c4       = (const float*)d_in[1];
    const float* c5       = (const float*)d_in[2];
    const float* dyn      = (const float*)d_in[3];
    const float* pnts     = (const float*)d_in[4];
    const int*   coors    = (const int*)d_in[5];
    const int*   contains = (const int*)d_in[6];
    float* out = (float*)d_out;

    // workspace layout (tiered)
    char* ws = (char*)d_ws;
    size_t off = 0;
    int* winner = (int*)(ws + off);     off += (size_t)NB * XSZ * YSZ * 4;    // 4 MiB
    int* counter = (int*)(ws + off);    off += 16;
    float4* recs = (float4*)(ws + off); off += (size_t)NB * NP * 16;          // 1.25 MB
    size_t base_need = off;
    float* c3t = (float*)(ws + off);    off += (size_t)NB * NC * HW3 * 4;
    float* c4t = (float*)(ws + off);    off += (size_t)NB * NC * HW4 * 4;
    float* c5t = (float*)(ws + off);    off += (size_t)NB * NC * HW5 * 4;
    size_t t_need = off;                                                       // ~15.6 MB
    float* cvals = (float*)(ws + off);  off += (size_t)NB * NP * NC * 4;       // 20.5 MB
    size_t full_need = off;                                                    // ~36 MB

    bool useT    = (ws_size >= t_need);
    bool useFull = (ws_size >= full_need) && useT;
    (void)base_need;

    hipMemsetAsync(winner, 0xFF, (size_t)NB * XSZ * YSZ * 4, stream);
    hipMemsetAsync(counter, 0, 4, stream);

    int npts = NB * NP;
    k_scatter<<<(npts + 255) / 256, 256, 0, stream>>>(coors, contains, winner);

    if (useT) {
        int t3 = NB * NC * HW3, t4 = NB * NC * HW4, t5 = NB * NC * HW5;
        k_transpose<<<(t3 + 255) / 256, 256, 0, stream>>>(c3, c3t, 48, 160, t3);
        k_transpose<<<(t4 + 255) / 256, 256, 0, stream>>>(c4, c4t, 24, 80, t4);
        k_transpose<<<(t5 + 255) / 256, 256, 0, stream>>>(c5, c5t, 12, 40, t5);
    }

    k_compact<<<(npts + 255) / 256, 256, 0, stream>>>(coors, contains, pnts,
                                                      winner, counter, recs);

    if (useFull) {
        // compute into compact buffer, then single coalesced dense write
        k_sample<<<npts, 64, 0, stream>>>(recs, counter, c3t, c4t, c5t, dyn,
                                          cvals, out, NC, 1, 1, 1, /*mode=*/0);
        k_writeout<<<NB * XSZ, 256, 0, stream>>>(winner, cvals, out);
    } else {
        // fallback: fast zero-fill + scattered stores
        long n4 = (long)out_size / 4;
        k_zero4<<<8192, 256, 0, stream>>>((float4*)out, n4);
        if (useT) {
            k_sample<<<npts, 64, 0, stream>>>(recs, counter, c3t, c4t, c5t, dyn,
                                              nullptr, out, NC, 1, 1, 1, /*mode=*/1);
        } else {
            k_sample<<<npts, 64, 0, stream>>>(recs, counter, c3, c4, c5, dyn,
                                              nullptr, out, 1, HW3, HW4, HW5, /*mode=*/1);
        }
    }
}

// Round 5
// 86.990 us; speedup vs baseline: 1.7811x; 1.4339x over previous
//
#include <hip/hip_runtime.h>
#include <cstddef>

#define XSZ 512
#define YSZ 512
#define NB  4
#define NC  64
#define NP  20000
#define H3 48
#define W3 160
#define H4 24
#define W4 80
#define H5 12
#define W5 40
#define HW3 (H3*W3)
#define HW4 (H4*W4)
#define HW5 (H5*W5)

#define FILL_BLOCKS 256                    // 256 blk * 256 thr * 4 int4 = 4 MiB winner fill
#define T3_TILES (NB * ((HW3 + 63) / 64))  // 480
#define T4_TILES (NB * ((HW4 + 63) / 64))  // 120
#define T5_TILES (NB * ((HW5 + 63) / 64))  // 32

// ---------------------------------------------------------------------------
// Fused init: winner <- -1 (int4 fill)  +  LDS-tiled transpose [B,C,H,W] ->
// [B,H,W,C] for all three images (reads AND writes coalesced, 64ch x 64pix
// tiles, pad 65 -> bank-conflict-free).
// ---------------------------------------------------------------------------
__global__ void __launch_bounds__(256)
k_init(int4* __restrict__ winner4,
       const float* __restrict__ c3, const float* __restrict__ c4,
       const float* __restrict__ c5,
       float* __restrict__ c3t, float* __restrict__ c4t, float* __restrict__ c5t) {
    int blk = blockIdx.x;
    if (blk < FILL_BLOCKS) {
        int base = blk * 1024 + threadIdx.x;
        int4 m1 = make_int4(-1, -1, -1, -1);
        winner4[base      ] = m1;
        winner4[base + 256] = m1;
        winner4[base + 512] = m1;
        winner4[base + 768] = m1;
        return;
    }
    __shared__ float lds[NC * 65];
    int t = blk - FILL_BLOCKS;
    const float* in; float* outp; int HW, tpb;
    if (t < T3_TILES)                      { in = c3; outp = c3t; HW = HW3; tpb = 120; }
    else if ((t -= T3_TILES) < T4_TILES)   { in = c4; outp = c4t; HW = HW4; tpb = 30; }
    else { t -= T4_TILES;                    in = c5; outp = c5t; HW = HW5; tpb = 8; }
    int b  = t / tpb;
    int p0 = (t - b * tpb) * 64;
    int lane = threadIdx.x & 63, wave = threadIdx.x >> 6;
    const float* in_b  = in   + (size_t)b * NC * HW;
    float*       out_b = outp + (size_t)b * HW * NC;

    int p = p0 + lane;
    if (p < HW) {
        for (int ch = wave; ch < NC; ch += 4)          // coalesced 256B reads
            lds[ch * 65 + lane] = in_b[(size_t)ch * HW + p];
    }
    __syncthreads();
    for (int pp = wave; pp < 64; pp += 4) {            // coalesced 256B writes
        int pq = p0 + pp;
        if (pq < HW) out_b[(size_t)pq * NC + lane] = lds[lane * 65 + pp];
    }
}

// ---------------------------------------------------------------------------
// Scatter: winner[b][cx][cy] = max point-index p with contains>0
// (numpy fancy-assignment last-write-wins == max p)
// ---------------------------------------------------------------------------
__global__ void __launch_bounds__(256)
k_scatter(const int* __restrict__ coors, const int* __restrict__ contains,
          int* __restrict__ winner) {
    int idx = blockIdx.x * blockDim.x + threadIdx.x;   // b*NP + p
    if (idx >= NB * NP) return;
    if (contains[idx] <= 0) return;
    int b  = idx / NP;
    int p  = idx - b * NP;
    int cx = coors[idx * 3 + 1];
    int cy = coors[idx * 3 + 2];
    if ((unsigned)cx >= XSZ || (unsigned)cy >= YSZ) return;   // mode='drop'
    atomicMax(&winner[((size_t)b * XSZ + cx) * YSZ + cy], p);
}

// ---------------------------------------------------------------------------
// Bilinear, exact f32 replay of the reference arithmetic. Transposed [H,W,C]
// layout: per-tap wave read = 64 consecutive floats = one 256B segment.
// ---------------------------------------------------------------------------
__device__ __forceinline__ float bilinT(const float* __restrict__ img, int H, int W,
                                        float px, float py, int c) {
    float gx = px * 2.0f - 1.0f;
    float gy = py * 2.0f - 1.0f;
    float x = (gx + 1.0f) * 0.5f * (float)(W - 1);
    float y = (gy + 1.0f) * 0.5f * (float)(H - 1);
    float x0f = floorf(x), y0f = floorf(y);
    float wx1 = x - x0f,   wy1 = y - y0f;
    float wx0 = 1.0f - wx1, wy0 = 1.0f - wy1;
    int x0 = (int)x0f, y0 = (int)y0f;
    float acc = 0.0f;
#pragma unroll
    for (int dy = 0; dy < 2; ++dy) {
#pragma unroll
        for (int dx = 0; dx < 2; ++dx) {
            int xi = x0 + dx, yi = y0 + dy;
            bool valid = (xi >= 0) && (xi <= W - 1) && (yi >= 0) && (yi <= H - 1);
            int xc = min(max(xi, 0), W - 1);
            int yc = min(max(yi, 0), H - 1);
            float w = (dx ? wx1 : wx0) * (dy ? wy1 : wy0);
            float v = img[(size_t)(yc * W + xc) * NC + c];
            acc = fmaf(v, valid ? w : 0.0f, acc);
        }
    }
    return acc;
}

// generic-stride variant for the no-transpose fallback
__device__ __forceinline__ float bilinG(const float* __restrict__ img, int H, int W,
                                        float px, float py, int c, int sChan) {
    float gx = px * 2.0f - 1.0f;
    float gy = py * 2.0f - 1.0f;
    float x = (gx + 1.0f) * 0.5f * (float)(W - 1);
    float y = (gy + 1.0f) * 0.5f * (float)(H - 1);
    float x0f = floorf(x), y0f = floorf(y);
    float wx1 = x - x0f,   wy1 = y - y0f;
    float wx0 = 1.0f - wx1, wy0 = 1.0f - wy1;
    int x0 = (int)x0f, y0 = (int)y0f;
    float acc = 0.0f;
#pragma unroll
    for (int dy = 0; dy < 2; ++dy) {
#pragma unroll
        for (int dx = 0; dx < 2; ++dx) {
            int xi = x0 + dx, yi = y0 + dy;
            bool valid = (xi >= 0) && (xi <= W - 1) && (yi >= 0) && (yi <= H - 1);
            int xc = min(max(xi, 0), W - 1);
            int yc = min(max(yi, 0), H - 1);
            float w = (dx ? wx1 : wx0) * (dy ? wy1 : wy0);
            float v = img[(size_t)(yc * W + xc) + (size_t)c * sChan];
            acc = fmaf(v, valid ? w : 0.0f, acc);
        }
    }
    return acc;
}

// ---------------------------------------------------------------------------
// Sample: grid-stride, one 64-lane wave per point, lane = channel.
// Winning points (winner[cell]==p) compute 3 bilinears and write the compact
// channel vector cvals[(b*NP+p)*64 + c] (coalesced 256B store). No compaction
// pass needed: winner[cell]=p IS the gather index for the writer.
// ---------------------------------------------------------------------------
__global__ void __launch_bounds__(256)
k_samp(const int* __restrict__ coors, const int* __restrict__ contains,
       const float* __restrict__ pnts, const int* __restrict__ winner,
       const float* __restrict__ i3t, const float* __restrict__ i4t,
       const float* __restrict__ i5t, const float* __restrict__ dyn,
       float* __restrict__ cvals) {
    int nw   = gridDim.x << 2;
    int wv   = (blockIdx.x << 2) + (threadIdx.x >> 6);
    int lane = threadIdx.x & 63;
    for (int idx = wv; idx < NB * NP; idx += nw) {
        if (contains[idx] <= 0) continue;
        int b = idx / NP;
        int p = idx - b * NP;
        int cx = coors[idx * 3 + 1];
        int cy = coors[idx * 3 + 2];
        if ((unsigned)cx >= XSZ || (unsigned)cy >= YSZ) continue;
        if (winner[((size_t)b * XSZ + cx) * YSZ + cy] != p) continue;
        float px = pnts[idx * 2], py = pnts[idx * 2 + 1];
        float fa = bilinT(i3t + (size_t)b * HW3 * NC, H3, W3, px, py, lane);
        float fb = bilinT(i4t + (size_t)b * HW4 * NC, H4, W4, px, py, lane);
        float fc = bilinT(i5t + (size_t)b * HW5 * NC, H5, W5, px, py, lane);
        size_t dbase = (((size_t)b * 3) * XSZ + cx) * YSZ + cy;
        float d0 = dyn[dbase];
        float d1 = dyn[dbase + (size_t)XSZ * YSZ];
        float d2 = dyn[dbase + (size_t)2 * XSZ * YSZ];
        cvals[(size_t)idx * NC + lane] = fa * d0 + fb * d1 + fc * d2;
    }
}

// fallback: scattered direct store into pre-zeroed out, untransposed images
__global__ void __launch_bounds__(256)
k_samp_fb(const int* __restrict__ coors, const int* __restrict__ contains,
          const float* __restrict__ pnts, const int* __restrict__ winner,
          const float* __restrict__ i3, const float* __restrict__ i4,
          const float* __restrict__ i5, const float* __restrict__ dyn,
          float* __restrict__ out) {
    int nw   = gridDim.x << 2;
    int wv   = (blockIdx.x << 2) + (threadIdx.x >> 6);
    int lane = threadIdx.x & 63;
    for (int idx = wv; idx < NB * NP; idx += nw) {
        if (contains[idx] <= 0) continue;
        int b = idx / NP;
        int p = idx - b * NP;
        int cx = coors[idx * 3 + 1];
        int cy = coors[idx * 3 + 2];
        if ((unsigned)cx >= XSZ || (unsigned)cy >= YSZ) continue;
        if (winner[((size_t)b * XSZ + cx) * YSZ + cy] != p) continue;
        float px = pnts[idx * 2], py = pnts[idx * 2 + 1];
        float fa = bilinG(i3 + (size_t)b * NC * HW3, H3, W3, px, py, lane, HW3);
        float fb = bilinG(i4 + (size_t)b * NC * HW4, H4, W4, px, py, lane, HW4);
        float fc = bilinG(i5 + (size_t)b * NC * HW5, H5, W5, px, py, lane, HW5);
        size_t dbase = (((size_t)b * 3) * XSZ + cx) * YSZ + cy;
        float d0 = dyn[dbase];
        float d1 = dyn[dbase + (size_t)XSZ * YSZ];
        float d2 = dyn[dbase + (size_t)2 * XSZ * YSZ];
        out[(((size_t)b * NC + lane) * XSZ + cx) * YSZ + cy] = fa * d0 + fb * d1 + fc * d2;
    }
}

// ---------------------------------------------------------------------------
// Dense writer: block owns one (b,x) slab out[b][:, x, :] (128 KB). Winner row
// register-cached as int4, reused across all 64 channels; every output byte
// written exactly once, float4-coalesced. Gather index = b*NP + winner_p.
// ---------------------------------------------------------------------------
__global__ void __launch_bounds__(256)
k_writeout(const int* __restrict__ winner, const float* __restrict__ cvals,
           float* __restrict__ out) {
    int bx = blockIdx.x;                 // b*512 + x
    int b = bx >> 9, x = bx & 511;
    const int4* wrow = (const int4*)(winner + ((size_t)b * XSZ + x) * YSZ);
    int4 r = wrow[threadIdx.x & 127];    // this thread's 4 consecutive y cells
    int lane_c = threadIdx.x >> 7;       // 0 or 1
    int y4 = (threadIdx.x & 127) << 2;
    size_t obase = (size_t)b * NC * XSZ * YSZ + (size_t)x * YSZ + y4;
    size_t pb = (size_t)b * NP;

    bool h0 = r.x >= 0, h1 = r.y >= 0, h2 = r.z >= 0, h3 = r.w >= 0;
    size_t s0 = (pb + (unsigned)r.x) * NC;   // used only when h* true
    size_t s1 = (pb + (unsigned)r.y) * NC;
    size_t s2 = (pb + (unsigned)r.z) * NC;
    size_t s3 = (pb + (unsigned)r.w) * NC;

    for (int cb = 0; cb < NC; cb += 2) {
        int c = cb + lane_c;
        float4 v = make_float4(0.f, 0.f, 0.f, 0.f);
        if (h0) v.x = cvals[s0 + c];
        if (h1) v.y = cvals[s1 + c];
        if (h2) v.z = cvals[s2 + c];
        if (h3) v.w = cvals[s3 + c];
        *(float4*)(out + obase + (size_t)c * (XSZ * YSZ)) = v;
    }
}

// fast zero-fill for fallback paths
__global__ void k_zero4(float4* __restrict__ p, long n4) {
    long i = (long)blockIdx.x * blockDim.x + threadIdx.x;
    long stride = (long)gridDim.x * blockDim.x;
    for (; i < n4; i += stride) p[i] = make_float4(0.f, 0.f, 0.f, 0.f);
}

extern "C" void kernel_launch(void* const* d_in, const int* in_sizes, int n_in,
                              void* d_out, int out_size, void* d_ws, size_t ws_size,
                              hipStream_t stream) {
    const float* c3       = (const float*)d_in[0];
    const float* c4       = (const float*)d_in[1];
    const float* c5       = (const float*)d_in[2];
    const float* dyn      = (const float*)d_in[3];
    const float* pnts     = (const float*)d_in[4];
    const int*   coors    = (const int*)d_in[5];
    const int*   contains = (const int*)d_in[6];
    float* out = (float*)d_out;

    // workspace layout
    char* ws = (char*)d_ws;
    size_t off = 0;
    int* winner = (int*)(ws + off);   off += (size_t)NB * XSZ * YSZ * 4;   // 4 MiB
    float* c3t  = (float*)(ws + off); off += (size_t)NB * NC * HW3 * 4;    // 7.9 MB
    float* c4t  = (float*)(ws + off); off += (size_t)NB * NC * HW4 * 4;    // 2.0 MB
    float* c5t  = (float*)(ws + off); off += (size_t)NB * NC * HW5 * 4;    // 0.5 MB
    size_t t_need = off;                                                    // ~14.5 MB
    float* cvals = (float*)(ws + off); off += (size_t)NB * NP * NC * 4;     // 20.5 MB
    size_t full_need = off;                                                 // ~35 MB

    bool useT    = (ws_size >= t_need);
    bool useFull = (ws_size >= full_need);

    int npts = NB * NP;
    int init_blocks = useT ? (FILL_BLOCKS + T3_TILES + T4_TILES + T5_TILES)
                           : FILL_BLOCKS;
    k_init<<<init_blocks, 256, 0, stream>>>((int4*)winner, c3, c4, c5,
                                            c3t, c4t, c5t);
    k_scatter<<<(npts + 255) / 256, 256, 0, stream>>>(coors, contains, winner);

    if (useFull) {
        // 4-dispatch main path: sample -> compact vectors, then exactly-once
        // coalesced dense write (no output zero-fill anywhere)
        k_samp<<<2048, 256, 0, stream>>>(coors, contains, pnts, winner,
                                         c3t, c4t, c5t, dyn, cvals);
        k_writeout<<<NB * XSZ, 256, 0, stream>>>(winner, cvals, out);
    } else {
        long n4 = (long)out_size / 4;
        k_zero4<<<8192, 256, 0, stream>>>((float4*)out, n4);
        if (useT) {
            // transposed images, scattered stores
            k_samp<<<2048, 256, 0, stream>>>(coors, contains, pnts, winner,
                                             c3t, c4t, c5t, dyn, nullptr);
            // note: cvals==nullptr unused in this branch; use fb writer instead
            k_samp_fb<<<2048, 256, 0, stream>>>(coors, contains, pnts, winner,
                                                c3, c4, c5, dyn, out);
        } else {
            k_samp_fb<<<2048, 256, 0, stream>>>(coors, contains, pnts, winner,
                                                c3, c4, c5, dyn, out);
        }
    }
}

// Round 6
// 75.734 us; speedup vs baseline: 2.0458x; 1.1486x over previous
//
#include <hip/hip_runtime.h>
#include <cstddef>

#define XSZ 512
#define YSZ 512
#define NB  4
#define NC  64
#define NP  20000
#define H3 48
#define W3 160
#define H4 24
#define W4 80
#define H5 12
#define W5 40
#define HW3 (H3*W3)
#define HW4 (H4*W4)
#define HW5 (H5*W5)
#define SLOT_CAP 128     // winners per row: mean ~19, Poisson max ~45; 128 is safe

#define FILL_BLOCKS 256                    // 256 blk * 256 thr * 4 int4 = 4 MiB winner fill
#define T3_TILES (NB * ((HW3 + 63) / 64))  // 480
#define T4_TILES (NB * ((HW4 + 63) / 64))  // 120
#define T5_TILES (NB * ((HW5 + 63) / 64))  // 32

// ---------------------------------------------------------------------------
// Fused init: winner <- -1 (int4 fill)  +  LDS-tiled transpose [B,C,H,W] ->
// [B,H,W,C] for all three images (reads AND writes coalesced).
// ---------------------------------------------------------------------------
__global__ void __launch_bounds__(256)
k_init(int4* __restrict__ winner4,
       const float* __restrict__ c3, const float* __restrict__ c4,
       const float* __restrict__ c5,
       float* __restrict__ c3t, float* __restrict__ c4t, float* __restrict__ c5t) {
    int blk = blockIdx.x;
    if (blk < FILL_BLOCKS) {
        int base = blk * 1024 + threadIdx.x;
        int4 m1 = make_int4(-1, -1, -1, -1);
        winner4[base      ] = m1;
        winner4[base + 256] = m1;
        winner4[base + 512] = m1;
        winner4[base + 768] = m1;
        return;
    }
    __shared__ float lds[NC * 65];
    int t = blk - FILL_BLOCKS;
    const float* in; float* outp; int HW, tpb;
    if (t < T3_TILES)                      { in = c3; outp = c3t; HW = HW3; tpb = 120; }
    else if ((t -= T3_TILES) < T4_TILES)   { in = c4; outp = c4t; HW = HW4; tpb = 30; }
    else { t -= T4_TILES;                    in = c5; outp = c5t; HW = HW5; tpb = 8; }
    int b  = t / tpb;
    int p0 = (t - b * tpb) * 64;
    int lane = threadIdx.x & 63, wave = threadIdx.x >> 6;
    const float* in_b  = in   + (size_t)b * NC * HW;
    float*       out_b = outp + (size_t)b * HW * NC;

    int p = p0 + lane;
    if (p < HW) {
        for (int ch = wave; ch < NC; ch += 4)          // coalesced 256B reads
            lds[ch * 65 + lane] = in_b[(size_t)ch * HW + p];
    }
    __syncthreads();
    for (int pp = wave; pp < 64; pp += 4) {            // coalesced 256B writes
        int pq = p0 + pp;
        if (pq < HW) out_b[(size_t)pq * NC + lane] = lds[lane * 65 + pp];
    }
}

// ---------------------------------------------------------------------------
// Scatter: winner[b][cx][cy] = max point-index p with contains>0
// (numpy fancy-assignment last-write-wins == max p)
// ---------------------------------------------------------------------------
__global__ void __launch_bounds__(256)
k_scatter(const int* __restrict__ coors, const int* __restrict__ contains,
          int* __restrict__ winner) {
    int idx = blockIdx.x * blockDim.x + threadIdx.x;   // b*NP + p
    if (idx >= NB * NP) return;
    if (contains[idx] <= 0) return;
    int b  = idx / NP;
    int p  = idx - b * NP;
    int cx = coors[idx * 3 + 1];
    int cy = coors[idx * 3 + 2];
    if ((unsigned)cx >= XSZ || (unsigned)cy >= YSZ) return;   // mode='drop'
    atomicMax(&winner[((size_t)b * XSZ + cx) * YSZ + cy], p);
}

// ---------------------------------------------------------------------------
// Bilinear, exact f32 replay of the reference arithmetic. Transposed [H,W,C]
// layout: per-tap wave read = 64 consecutive floats = one 256B segment.
// ---------------------------------------------------------------------------
__device__ __forceinline__ float bilinT(const float* __restrict__ img, int H, int W,
                                        float px, float py, int c) {
    float gx = px * 2.0f - 1.0f;
    float gy = py * 2.0f - 1.0f;
    float x = (gx + 1.0f) * 0.5f * (float)(W - 1);
    float y = (gy + 1.0f) * 0.5f * (float)(H - 1);
    float x0f = floorf(x), y0f = floorf(y);
    float wx1 = x - x0f,   wy1 = y - y0f;
    float wx0 = 1.0f - wx1, wy0 = 1.0f - wy1;
    int x0 = (int)x0f, y0 = (int)y0f;
    float acc = 0.0f;
#pragma unroll
    for (int dy = 0; dy < 2; ++dy) {
#pragma unroll
        for (int dx = 0; dx < 2; ++dx) {
            int xi = x0 + dx, yi = y0 + dy;
            bool valid = (xi >= 0) && (xi <= W - 1) && (yi >= 0) && (yi <= H - 1);
            int xc = min(max(xi, 0), W - 1);
            int yc = min(max(yi, 0), H - 1);
            float w = (dx ? wx1 : wx0) * (dy ? wy1 : wy0);
            float v = img[(size_t)(yc * W + xc) * NC + c];
            acc = fmaf(v, valid ? w : 0.0f, acc);
        }
    }
    return acc;
}

// generic-stride variant for the no-transpose fallback
__device__ __forceinline__ float bilinG(const float* __restrict__ img, int H, int W,
                                        float px, float py, int c, int sChan) {
    float gx = px * 2.0f - 1.0f;
    float gy = py * 2.0f - 1.0f;
    float x = (gx + 1.0f) * 0.5f * (float)(W - 1);
    float y = (gy + 1.0f) * 0.5f * (float)(H - 1);
    float x0f = floorf(x), y0f = floorf(y);
    float wx1 = x - x0f,   wy1 = y - y0f;
    float wx0 = 1.0f - wx1, wy0 = 1.0f - wy1;
    int x0 = (int)x0f, y0 = (int)y0f;
    float acc = 0.0f;
#pragma unroll
    for (int dy = 0; dy < 2; ++dy) {
#pragma unroll
        for (int dx = 0; dx < 2; ++dx) {
            int xi = x0 + dx, yi = y0 + dy;
            bool valid = (xi >= 0) && (xi <= W - 1) && (yi >= 0) && (yi <= H - 1);
            int xc = min(max(xi, 0), W - 1);
            int yc = min(max(yi, 0), H - 1);
            float w = (dx ? wx1 : wx0) * (dy ? wy1 : wy0);
            float v = img[(size_t)(yc * W + xc) + (size_t)c * sChan];
            acc = fmaf(v, valid ? w : 0.0f, acc);
        }
    }
    return acc;
}

// ---------------------------------------------------------------------------
// Fused sample + dense writer. One block per (b,x) output slab (64c x 512y,
// 128 KB). Phase A: scan winner row, build slot list (LDS). Phase B: one wave
// per winning cell computes the 3 bilinears (lane=channel, coalesced 256B
// taps) into vec[slot][65] (pad 65 -> conflict-free write (s+lane)%32 and
// read (s+c)%32). Phase C: exactly-once float4-coalesced dense write, gather
// from LDS. Phase D: overflow cells (>SLOT_CAP winners/row; ~never) scattered.
// ---------------------------------------------------------------------------
__global__ void __launch_bounds__(256)
k_fused(const float* __restrict__ pnts, const int* __restrict__ winner,
        const float* __restrict__ i3t, const float* __restrict__ i4t,
        const float* __restrict__ i5t, const float* __restrict__ dyn,
        float* __restrict__ out) {
    __shared__ float vec[SLOT_CAP * 65];
    __shared__ int smap[YSZ];
    __shared__ int slist[YSZ];
    __shared__ int ylist[YSZ];
    __shared__ int cnt;

    int bx = blockIdx.x;                 // b*512 + x
    int b = bx >> 9, x = bx & 511;
    int tid = threadIdx.x;
    if (tid == 0) cnt = 0;
    __syncthreads();

    // --- phase A: row scan, slot assignment ---
    const int2* wrow2 = (const int2*)(winner + ((size_t)b * XSZ + x) * YSZ);
    int2 r2 = wrow2[tid];                // 2 consecutive y cells per thread
    {
        int y0 = tid * 2;
        int pv0 = r2.x, pv1 = r2.y;
        int s0 = -1, s1 = -1;
        if (pv0 >= 0) { s0 = atomicAdd(&cnt, 1); slist[s0] = pv0; ylist[s0] = y0; }
        if (pv1 >= 0) { s1 = atomicAdd(&cnt, 1); slist[s1] = pv1; ylist[s1] = y0 + 1; }
        smap[y0]     = s0;
        smap[y0 + 1] = s1;
    }
    __syncthreads();
    int n = cnt;
    int nB = min(n, SLOT_CAP);

    // --- phase B: compute winning-cell channel vectors into LDS ---
    int wave = tid >> 6, lane = tid & 63;
    const float* i3b = i3t + (size_t)b * HW3 * NC;
    const float* i4b = i4t + (size_t)b * HW4 * NC;
    const float* i5b = i5t + (size_t)b * HW5 * NC;
    for (int s = wave; s < nB; s += 4) {
        int p = slist[s], y = ylist[s];
        int idx = b * NP + p;
        float px = pnts[idx * 2], py = pnts[idx * 2 + 1];
        float fa = bilinT(i3b, H3, W3, px, py, lane);
        float fb = bilinT(i4b, H4, W4, px, py, lane);
        float fc = bilinT(i5b, H5, W5, px, py, lane);
        size_t dbase = (((size_t)b * 3) * XSZ + x) * YSZ + y;
        float d0 = dyn[dbase];
        float d1 = dyn[dbase + (size_t)XSZ * YSZ];
        float d2 = dyn[dbase + (size_t)2 * XSZ * YSZ];
        vec[s * 65 + lane] = fa * d0 + fb * d1 + fc * d2;
    }
    __syncthreads();

    // --- phase C: exactly-once coalesced dense write ---
    int lane_c = tid >> 7;               // 0 or 1
    int t7 = tid & 127;
    int y4 = t7 << 2;
    int s0 = smap[y4], s1 = smap[y4 + 1], s2 = smap[y4 + 2], s3 = smap[y4 + 3];
    bool h0 = (unsigned)s0 < SLOT_CAP, h1 = (unsigned)s1 < SLOT_CAP;
    bool h2 = (unsigned)s2 < SLOT_CAP, h3 = (unsigned)s3 < SLOT_CAP;
    size_t obase = (size_t)b * NC * XSZ * YSZ + (size_t)x * YSZ + y4;
    for (int cb = 0; cb < NC; cb += 2) {
        int c = cb + lane_c;
        float4 v = make_float4(0.f, 0.f, 0.f, 0.f);
        if (h0) v.x = vec[s0 * 65 + c];
        if (h1) v.y = vec[s1 * 65 + c];
        if (h2) v.z = vec[s2 * 65 + c];
        if (h3) v.w = vec[s3 * 65 + c];
        *(float4*)(out + obase + (size_t)c * (XSZ * YSZ)) = v;
    }

    // --- phase D: overflow slots (practically never taken) ---
    if (n > SLOT_CAP) {
        __syncthreads();                 // order after phase-C zeros
        for (int s = SLOT_CAP + wave; s < n; s += 4) {
            int p = slist[s], y = ylist[s];
            int idx = b * NP + p;
            float px = pnts[idx * 2], py = pnts[idx * 2 + 1];
            float fa = bilinT(i3b, H3, W3, px, py, lane);
            float fb = bilinT(i4b, H4, W4, px, py, lane);
            float fc = bilinT(i5b, H5, W5, px, py, lane);
            size_t dbase = (((size_t)b * 3) * XSZ + x) * YSZ + y;
            float d0 = dyn[dbase];
            float d1 = dyn[dbase + (size_t)XSZ * YSZ];
            float d2 = dyn[dbase + (size_t)2 * XSZ * YSZ];
            out[(((size_t)b * NC + lane) * XSZ + x) * YSZ + y] =
                fa * d0 + fb * d1 + fc * d2;
        }
    }
}

// fallback: scattered direct store into pre-zeroed out, untransposed images
__global__ void __launch_bounds__(256)
k_samp_fb(const int* __restrict__ coors, const int* __restrict__ contains,
          const float* __restrict__ pnts, const int* __restrict__ winner,
          const float* __restrict__ i3, const float* __restrict__ i4,
          const float* __restrict__ i5, const float* __restrict__ dyn,
          float* __restrict__ out) {
    int nw   = gridDim.x << 2;
    int wv   = (blockIdx.x << 2) + (threadIdx.x >> 6);
    int lane = threadIdx.x & 63;
    for (int idx = wv; idx < NB * NP; idx += nw) {
        if (contains[idx] <= 0) continue;
        int b = idx / NP;
        int p = idx - b * NP;
        int cx = coors[idx * 3 + 1];
        int cy = coors[idx * 3 + 2];
        if ((unsigned)cx >= XSZ || (unsigned)cy >= YSZ) continue;
        if (winner[((size_t)b * XSZ + cx) * YSZ + cy] != p) continue;
        float px = pnts[idx * 2], py = pnts[idx * 2 + 1];
        float fa = bilinG(i3 + (size_t)b * NC * HW3, H3, W3, px, py, lane, HW3);
        float fb = bilinG(i4 + (size_t)b * NC * HW4, H4, W4, px, py, lane, HW4);
        float fc = bilinG(i5 + (size_t)b * NC * HW5, H5, W5, px, py, lane, HW5);
        size_t dbase = (((size_t)b * 3) * XSZ + cx) * YSZ + cy;
        float d0 = dyn[dbase];
        float d1 = dyn[dbase + (size_t)XSZ * YSZ];
        float d2 = dyn[dbase + (size_t)2 * XSZ * YSZ];
        out[(((size_t)b * NC + lane) * XSZ + cx) * YSZ + cy] = fa * d0 + fb * d1 + fc * d2;
    }
}

// fast zero-fill for fallback path
__global__ void k_zero4(float4* __restrict__ p, long n4) {
    long i = (long)blockIdx.x * blockDim.x + threadIdx.x;
    long stride = (long)gridDim.x * blockDim.x;
    for (; i < n4; i += stride) p[i] = make_float4(0.f, 0.f, 0.f, 0.f);
}

extern "C" void kernel_launch(void* const* d_in, const int* in_sizes, int n_in,
                              void* d_out, int out_size, void* d_ws, size_t ws_size,
                              hipStream_t stream) {
    const float* c3       = (const float*)d_in[0];
    const float* c4       = (const float*)d_in[1];
    const float* c5       = (const float*)d_in[2];
    const float* dyn      = (const float*)d_in[3];
    const float* pnts     = (const float*)d_in[4];
    const int*   coors    = (const int*)d_in[5];
    const int*   contains = (const int*)d_in[6];
    float* out = (float*)d_out;

    // workspace layout
    char* ws = (char*)d_ws;
    size_t off = 0;
    int* winner = (int*)(ws + off);   off += (size_t)NB * XSZ * YSZ * 4;   // 4 MiB
    float* c3t  = (float*)(ws + off); off += (size_t)NB * NC * HW3 * 4;    // 7.9 MB
    float* c4t  = (float*)(ws + off); off += (size_t)NB * NC * HW4 * 4;    // 2.0 MB
    float* c5t  = (float*)(ws + off); off += (size_t)NB * NC * HW5 * 4;    // 0.5 MB
    size_t t_need = off;                                                    // ~14.5 MB
    bool useT = (ws_size >= t_need);

    int npts = NB * NP;
    int init_blocks = useT ? (FILL_BLOCKS + T3_TILES + T4_TILES + T5_TILES)
                           : FILL_BLOCKS;
    k_init<<<init_blocks, 256, 0, stream>>>((int4*)winner, c3, c4, c5,
                                            c3t, c4t, c5t);
    k_scatter<<<(npts + 255) / 256, 256, 0, stream>>>(coors, contains, winner);

    if (useT) {
        // 3-dispatch main path: no output zero-fill, no intermediate buffer
        k_fused<<<NB * XSZ, 256, 0, stream>>>(pnts, winner, c3t, c4t, c5t,
                                              dyn, out);
    } else {
        long n4 = (long)out_size / 4;
        k_zero4<<<8192, 256, 0, stream>>>((float4*)out, n4);
        k_samp_fb<<<2048, 256, 0, stream>>>(coors, contains, pnts, winner,
                                            c3, c4, c5, dyn, out);
    }
}